// Round 2
// baseline (2881.451 us; speedup 1.0000x reference)
//
#include <hip/hip_runtime.h>
#include <cmath>

// Problem constants
#define B_   512
#define L_   200
#define V_   50000
#define E_   256
#define H_   128     // per-direction hidden
#define G4H_ 512     // 4*H
#define D_   256     // 2*H
#define T_   6

__device__ __forceinline__ float sigmoidf_(float x) { return 1.0f / (1.0f + __expf(-x)); }
__device__ __forceinline__ float leakyf_(float x)   { return x >= 0.0f ? x : 0.01f * x; }

// ---------------------------------------------------------------------------
// K1: xg GEMM for a time-chunk, both directions.
// Virtual row vm in [0, 2*B*tc): dir = vm >= B*tc; rem -> (b, ti); s = c0+ti;
// t = dir ? L-1-s : s.  C[vm][n] = emb[sent[b][t]] . W[dir][n][:] + bias[dir][n]
// Output layout xgc[vm][512] (vm-major), consumed sequentially by the scan.
// Tiles: BM=64, BN=128, BK=16, 256 threads, 4x8 micro-tile.
// ---------------------------------------------------------------------------
#define BM 64
#define BN 128
#define BK 16

__global__ __launch_bounds__(256) void gemm_xg_chunk(
    const int* __restrict__ sent, const float* __restrict__ emb,
    const float* __restrict__ Wf, const float* __restrict__ Wb,
    const float* __restrict__ bihf, const float* __restrict__ bhhf,
    const float* __restrict__ bihb, const float* __restrict__ bhhb,
    float* __restrict__ xgc, int c0, int tc)
{
    __shared__ float As[BK][BM];
    __shared__ float Bs[BK][BN];
    __shared__ int   tok[BM];

    const int bm  = blockIdx.x;       // 0 .. 16*tc-1
    const int bn  = blockIdx.y;       // 0..3 (N=512 per dir)
    const int tid = threadIdx.x;
    const int half = B_ * tc;         // rows per direction
    const int dir  = (bm * BM) >= half;   // uniform per block (B*tc % 64 == 0)

    if (tid < BM) {
        const int vm  = bm * BM + tid;
        const int rem = vm - dir * half;
        const int b   = rem / tc;
        const int ti  = rem - b * tc;
        const int s   = c0 + ti;
        const int t   = dir ? (L_ - 1 - s) : s;
        tok[tid] = sent[b * L_ + t];
    }
    __syncthreads();

    const int tx = tid & 15;    // n groups of 8
    const int ty = tid >> 4;    // m groups of 4
    const int n0 = bn * BN;

    const float* W   = dir ? Wb   : Wf;
    const float* bih = dir ? bihb : bihf;
    const float* bhh = dir ? bhhb : bhhf;

    float acc[4][8];
#pragma unroll
    for (int i = 0; i < 4; ++i)
#pragma unroll
        for (int j = 0; j < 8; ++j) acc[i][j] = 0.0f;

    const int lrow = tid >> 2;          // 0..63
    const int lk   = (tid & 3) * 4;     // 0,4,8,12

    for (int k0 = 0; k0 < E_; k0 += BK) {
        // stage A (gathered from embedding)
        {
            const float4 v = *(const float4*)(emb + (size_t)tok[lrow] * E_ + k0 + lk);
            As[lk + 0][lrow] = v.x; As[lk + 1][lrow] = v.y;
            As[lk + 2][lrow] = v.z; As[lk + 3][lrow] = v.w;
        }
        // stage B = W^T (two passes of 64 rows)
#pragma unroll
        for (int p = 0; p < 2; ++p) {
            const int n = p * 64 + lrow;
            const float4 v = *(const float4*)(W + (size_t)(n0 + n) * E_ + k0 + lk);
            Bs[lk + 0][n] = v.x; Bs[lk + 1][n] = v.y;
            Bs[lk + 2][n] = v.z; Bs[lk + 3][n] = v.w;
        }
        __syncthreads();

#pragma unroll
        for (int k = 0; k < BK; ++k) {
            float a[4], bb[8];
            *(float4*)a        = *(const float4*)&As[k][ty * 4];
            *(float4*)(bb)     = *(const float4*)&Bs[k][tx * 8];
            *(float4*)(bb + 4) = *(const float4*)&Bs[k][tx * 8 + 4];
#pragma unroll
            for (int i = 0; i < 4; ++i)
#pragma unroll
                for (int j = 0; j < 8; ++j) acc[i][j] += a[i] * bb[j];
        }
        __syncthreads();
    }

    // epilogue: add bias, store vm-major
    const int nb = n0 + tx * 8;
    float bias[8];
#pragma unroll
    for (int j = 0; j < 8; ++j) bias[j] = bih[nb + j] + bhh[nb + j];
#pragma unroll
    for (int i = 0; i < 4; ++i) {
        const int vm = bm * BM + ty * 4 + i;
        float* dst = xgc + (size_t)vm * G4H_ + nb;
        float4 v0, v1;
        v0.x = acc[i][0] + bias[0]; v0.y = acc[i][1] + bias[1];
        v0.z = acc[i][2] + bias[2]; v0.w = acc[i][3] + bias[3];
        v1.x = acc[i][4] + bias[4]; v1.y = acc[i][5] + bias[5];
        v1.z = acc[i][6] + bias[6]; v1.w = acc[i][7] + bias[7];
        *(float4*)dst       = v0;
        *(float4*)(dst + 4) = v1;
    }
}

// ---------------------------------------------------------------------------
// K2: LSTM scan over one time-chunk. One block per (dir, group of GS samples).
// 512 threads: thread r owns gate-row r (Whh row r in VGPRs). h,c state
// persists across chunk launches in `state` (zero-initialized when c0==0).
// state layout: [dir][b][{h,c}][H]
// ---------------------------------------------------------------------------
#define GS 4

__global__ __launch_bounds__(512, 2) void lstm_scan_chunk(
    const float* __restrict__ xgc,
    const float* __restrict__ Whh_f, const float* __restrict__ Whh_b,
    float* __restrict__ state, float* __restrict__ hcat, int c0, int tc)
{
    const int wg  = blockIdx.x;      // 0..255
    const int dir = wg >> 7;
    const int b0  = (wg & 127) * GS;
    const int r   = threadIdx.x;     // 0..511

    const float* Whh = dir ? Whh_b : Whh_f;

    // Whh row r -> registers (128 floats)
    float w[H_];
#pragma unroll
    for (int k = 0; k < H_; k += 4) {
        const float4 v = *(const float4*)(Whh + (size_t)r * H_ + k);
        w[k] = v.x; w[k + 1] = v.y; w[k + 2] = v.z; w[k + 3] = v.w;
    }

    __shared__ float h_s[H_][GS];
    __shared__ float g_s[G4H_][GS];

    float c[GS] = {0.f, 0.f, 0.f, 0.f};   // live only for r < H_
    if (r < H_) {
        if (c0 == 0) {
            *(float4*)&h_s[r][0] = make_float4(0.f, 0.f, 0.f, 0.f);
        } else {
#pragma unroll
            for (int s = 0; s < GS; ++s) {
                h_s[r][s] = state[((size_t)(dir * B_ + b0 + s) * 2 + 0) * H_ + r];
                c[s]      = state[((size_t)(dir * B_ + b0 + s) * 2 + 1) * H_ + r];
            }
        }
    }

    const int t0    = dir ? (L_ - 1 - c0) : c0;
    const int hstep = dir ? -D_ : D_;

    const float* xp[GS];
    float* hp[GS];
#pragma unroll
    for (int s = 0; s < GS; ++s) {
        xp[s] = xgc + ((size_t)(dir * B_ + b0 + s) * tc) * G4H_ + r;
        hp[s] = hcat + ((size_t)(b0 + s) * L_ + t0) * D_ + dir * H_ + r;
    }
    __syncthreads();

    for (int t = 0; t < tc; ++t) {
        float a0 = xp[0][0], a1 = xp[1][0], a2 = xp[2][0], a3 = xp[3][0];
#pragma unroll
        for (int s = 0; s < GS; ++s) xp[s] += G4H_;

#pragma unroll
        for (int k = 0; k < H_; ++k) {
            const float4 hv = *(const float4*)&h_s[k][0];
            a0 += w[k] * hv.x;
            a1 += w[k] * hv.y;
            a2 += w[k] * hv.z;
            a3 += w[k] * hv.w;
        }
        *(float4*)&g_s[r][0] = make_float4(a0, a1, a2, a3);
        __syncthreads();

        if (r < H_) {
            const float4 gi = *(const float4*)&g_s[r][0];
            const float4 gf = *(const float4*)&g_s[r + H_][0];
            const float4 gg = *(const float4*)&g_s[r + 2 * H_][0];
            const float4 go = *(const float4*)&g_s[r + 3 * H_][0];
            float hv[GS];
            c[0] = sigmoidf_(gf.x) * c[0] + sigmoidf_(gi.x) * tanhf(gg.x);
            hv[0] = sigmoidf_(go.x) * tanhf(c[0]);
            c[1] = sigmoidf_(gf.y) * c[1] + sigmoidf_(gi.y) * tanhf(gg.y);
            hv[1] = sigmoidf_(go.y) * tanhf(c[1]);
            c[2] = sigmoidf_(gf.z) * c[2] + sigmoidf_(gi.z) * tanhf(gg.z);
            hv[2] = sigmoidf_(go.z) * tanhf(c[2]);
            c[3] = sigmoidf_(gf.w) * c[3] + sigmoidf_(gi.w) * tanhf(gg.w);
            hv[3] = sigmoidf_(go.w) * tanhf(c[3]);
            *(float4*)&h_s[r][0] = make_float4(hv[0], hv[1], hv[2], hv[3]);
#pragma unroll
            for (int s = 0; s < GS; ++s) { hp[s][0] = hv[s]; hp[s] += hstep; }
        }
        __syncthreads();
    }

    // save state for next chunk (threads wrote h_s[r] themselves; no sync needed)
    if (r < H_) {
#pragma unroll
        for (int s = 0; s < GS; ++s) {
            state[((size_t)(dir * B_ + b0 + s) * 2 + 0) * H_ + r] = h_s[r][s];
            state[((size_t)(dir * B_ + b0 + s) * 2 + 1) * H_ + r] = c[s];
        }
    }
}

// ---------------------------------------------------------------------------
// K3: fused MLP1 + MLP2 + tag projection.
// Per block: 32 rows. h1/h2 live in LDS (transposed [n][m], pad 34 to kill
// bank conflicts); logits written directly. No h1/h2 global buffers.
// ---------------------------------------------------------------------------
__global__ __launch_bounds__(256) void fused_mlp(
    const float* __restrict__ hcat,
    const float* __restrict__ W1, const float* __restrict__ b1,
    const float* __restrict__ W2, const float* __restrict__ b2,
    const float* __restrict__ Wt, const float* __restrict__ bt,
    float* __restrict__ logits)
{
    __shared__ float h1t[D_][34];      // [n][m], holds h1 then h2
    __shared__ float As2[BK][32];
    __shared__ float Bs2[BK][BN];
    __shared__ float Wt_s[T_][258];
    __shared__ float b1_s[D_], b2_s[D_], bt_s[T_];

    const int tid  = threadIdx.x;
    const int row0 = blockIdx.x * 32;

    for (int i = tid; i < T_ * D_; i += 256) Wt_s[i >> 8][i & 255] = Wt[i];
    b1_s[tid] = b1[tid];
    b2_s[tid] = b2[tid];
    if (tid < T_) bt_s[tid] = bt[tid];

    const int tx = tid & 15;          // n groups of 8
    const int ty = tid >> 4;          // m groups of 2 (0..15)
    const int lrow   = tid >> 3;      // As staging: row 0..31
    const int lk2    = (tid & 7) * 2; //             k pair
    const int lrow64 = tid >> 2;      // Bs staging: n 0..63 (x2 passes)
    const int lk4    = (tid & 3) * 4;

    // ---- GEMM1: h1 = leaky(hcat_tile @ W1^T + b1) -> h1t[n][m] ----
    for (int n0 = 0; n0 < D_; n0 += BN) {
        float acc[2][8];
#pragma unroll
        for (int i = 0; i < 2; ++i)
#pragma unroll
            for (int j = 0; j < 8; ++j) acc[i][j] = 0.0f;

        for (int k0 = 0; k0 < D_; k0 += BK) {
            const float2 av = *(const float2*)(hcat + (size_t)(row0 + lrow) * D_ + k0 + lk2);
            As2[lk2][lrow] = av.x; As2[lk2 + 1][lrow] = av.y;
#pragma unroll
            for (int p = 0; p < 2; ++p) {
                const int n = p * 64 + lrow64;
                const float4 wv = *(const float4*)(W1 + (size_t)(n0 + n) * D_ + k0 + lk4);
                Bs2[lk4 + 0][n] = wv.x; Bs2[lk4 + 1][n] = wv.y;
                Bs2[lk4 + 2][n] = wv.z; Bs2[lk4 + 3][n] = wv.w;
            }
            __syncthreads();
#pragma unroll
            for (int k = 0; k < BK; ++k) {
                const float2 a = *(const float2*)&As2[k][ty * 2];
                float bb[8];
                *(float4*)(bb)     = *(const float4*)&Bs2[k][tx * 8];
                *(float4*)(bb + 4) = *(const float4*)&Bs2[k][tx * 8 + 4];
#pragma unroll
                for (int j = 0; j < 8; ++j) {
                    acc[0][j] += a.x * bb[j];
                    acc[1][j] += a.y * bb[j];
                }
            }
            __syncthreads();
        }
#pragma unroll
        for (int i = 0; i < 2; ++i)
#pragma unroll
            for (int j = 0; j < 8; ++j) {
                const int n = n0 + tx * 8 + j;
                h1t[n][ty * 2 + i] = leakyf_(acc[i][j] + b1_s[n]);
            }
    }
    __syncthreads();

    // ---- GEMM2: h2 = leaky(h1 @ W2^T + b2), A read from h1t ----
    float acc2[2][2][8];
#pragma unroll
    for (int q = 0; q < 2; ++q)
#pragma unroll
        for (int i = 0; i < 2; ++i)
#pragma unroll
            for (int j = 0; j < 8; ++j) acc2[q][i][j] = 0.0f;

    for (int n0t = 0; n0t < 2; ++n0t) {
        const int n0 = n0t * BN;
        for (int k0 = 0; k0 < D_; k0 += BK) {
#pragma unroll
            for (int p = 0; p < 2; ++p) {
                const int n = p * 64 + lrow64;
                const float4 wv = *(const float4*)(W2 + (size_t)(n0 + n) * D_ + k0 + lk4);
                Bs2[lk4 + 0][n] = wv.x; Bs2[lk4 + 1][n] = wv.y;
                Bs2[lk4 + 2][n] = wv.z; Bs2[lk4 + 3][n] = wv.w;
            }
            __syncthreads();
#pragma unroll
            for (int k = 0; k < BK; ++k) {
                const float2 a = *(const float2*)&h1t[k0 + k][ty * 2];
                float bb[8];
                *(float4*)(bb)     = *(const float4*)&Bs2[k][tx * 8];
                *(float4*)(bb + 4) = *(const float4*)&Bs2[k][tx * 8 + 4];
#pragma unroll
                for (int j = 0; j < 8; ++j) {
                    acc2[n0t][0][j] += a.x * bb[j];
                    acc2[n0t][1][j] += a.y * bb[j];
                }
            }
            __syncthreads();
        }
    }
    // all h1t reads complete (loop ends with barrier) -> overwrite with h2
#pragma unroll
    for (int q = 0; q < 2; ++q)
#pragma unroll
        for (int i = 0; i < 2; ++i)
#pragma unroll
            for (int j = 0; j < 8; ++j) {
                const int n = q * BN + tx * 8 + j;
                h1t[n][ty * 2 + i] = leakyf_(acc2[q][i][j] + b2_s[n]);
            }
    __syncthreads();

    // ---- tag: logits = leaky(h2 @ Wt^T + bt) ----
    if (tid < 32 * T_) {
        const int m = tid / T_;
        const int j = tid - m * T_;
        float acc = 0.0f;
#pragma unroll 8
        for (int k = 0; k < D_; ++k) acc += h1t[k][m] * Wt_s[j][k];
        logits[(size_t)(row0 + m) * T_ + j] = leakyf_(acc + bt_s[j]);
    }
}

// ---------------------------------------------------------------------------
// K4: Viterbi per sample. Block = 64 threads (1 wave), grid = B.
// ---------------------------------------------------------------------------
__global__ __launch_bounds__(64) void viterbi_kernel(
    const float* __restrict__ logits, const float* __restrict__ trans,
    float* __restrict__ out)
{
    const int b = blockIdx.x;
    const int lane = threadIdx.x;

    __shared__ float prev[2][8];
    __shared__ unsigned char bp[L_][8];
    __shared__ int path_s[L_];

    float tr[T_];
    if (lane < T_) {
#pragma unroll
        for (int i = 0; i < T_; ++i) tr[i] = trans[i * T_ + lane];
    }
    const float* lg = logits + (size_t)b * L_ * T_;
    if (lane < T_) prev[0][lane] = lg[lane];
    __syncthreads();

    int cur = 0;
    for (int t = 1; t < L_; ++t) {
        if (lane < T_) {
            float m = -1e30f; int arg = 0;
#pragma unroll
            for (int i = 0; i < T_; ++i) {
                const float v = prev[cur][i] + tr[i];
                if (v > m) { m = v; arg = i; }
            }
            prev[1 - cur][lane] = lg[t * T_ + lane] + m;
            bp[t][lane] = (unsigned char)arg;
        }
        cur ^= 1;
        __syncthreads();
    }

    if (lane == 0) {
        float best = prev[cur][0]; int tag = 0;
#pragma unroll
        for (int j = 1; j < T_; ++j)
            if (prev[cur][j] > best) { best = prev[cur][j]; tag = j; }
        out[b] = best;
        path_s[L_ - 1] = tag;
        for (int t = L_ - 1; t >= 1; --t) {
            tag = bp[t][tag];
            path_s[t - 1] = tag;
        }
    }
    __syncthreads();
    for (int i = lane; i < L_; i += 64)
        out[B_ + (size_t)b * L_ + i] = (float)path_s[i];
}

// ---------------------------------------------------------------------------
extern "C" void kernel_launch(void* const* d_in, const int* in_sizes, int n_in,
                              void* d_out, int out_size, void* d_ws, size_t ws_size,
                              hipStream_t stream)
{
    (void)in_sizes; (void)n_in; (void)out_size;

    const int*   sent  = (const int*)  d_in[0];
    // d_in[1] real_length unused (all == L)
    const float* emb   = (const float*)d_in[2];
    const float* Wih_f = (const float*)d_in[3];
    const float* Whh_f = (const float*)d_in[4];
    const float* bih_f = (const float*)d_in[5];
    const float* bhh_f = (const float*)d_in[6];
    const float* Wih_b = (const float*)d_in[7];
    const float* Whh_b = (const float*)d_in[8];
    const float* bih_b = (const float*)d_in[9];
    const float* bhh_b = (const float*)d_in[10];
    const float* W1    = (const float*)d_in[11];
    const float* b1    = (const float*)d_in[12];
    const float* W2    = (const float*)d_in[13];
    const float* b2    = (const float*)d_in[14];
    const float* Wt    = (const float*)d_in[15];
    const float* bt    = (const float*)d_in[16];
    const float* trans = (const float*)d_in[17];

    float* ws = (float*)d_ws;
    const size_t HCAT_E = (size_t)B_ * L_ * D_;     // 26,214,400 floats
    const size_t LG_E   = (size_t)B_ * L_ * T_;     //    614,400
    const size_t ST_E   = (size_t)2 * B_ * 2 * H_;  //    262,144
    float* hcat   = ws;
    float* logits = ws + HCAT_E;
    float* state  = logits + LG_E;
    float* xgc    = state + ST_E;

    // Adaptive time-chunk so the xg staging buffer fits in ws_size.
    const size_t base  = HCAT_E + LG_E + ST_E;      // 27,090,944 floats (~108 MB)
    const size_t per_t = (size_t)2 * B_ * G4H_;     // 524,288 floats per timestep
    const size_t ws_f  = ws_size / sizeof(float);
    long long avail = (long long)ws_f - (long long)base;
    int Tc = (avail > 0) ? (int)(avail / (long long)per_t) : 0;
    if (Tc < 1)  Tc = 1;
    if (Tc > L_) Tc = L_;

    float* out = (float*)d_out;

    for (int c0 = 0; c0 < L_; c0 += Tc) {
        const int tc = (L_ - c0 < Tc) ? (L_ - c0) : Tc;
        // 1. xg chunk = emb[sent] @ Wih^T + (bih + bhh), both dirs
        gemm_xg_chunk<<<dim3(16 * tc, 4), 256, 0, stream>>>(
            sent, emb, Wih_f, Wih_b, bih_f, bhh_f, bih_b, bhh_b, xgc, c0, tc);
        // 2. scan the chunk (state carried in ws)
        lstm_scan_chunk<<<256, 512, 0, stream>>>(
            xgc, Whh_f, Whh_b, state, hcat, c0, tc);
    }
    // 3-5. fused MLP1 + MLP2 + tag -> logits
    fused_mlp<<<(B_ * L_) / 32, 256, 0, stream>>>(
        hcat, W1, b1, W2, b2, Wt, bt, logits);
    // 6. Viterbi decode -> scores [512], paths [512*200] (as float)
    viterbi_kernel<<<B_, 64, 0, stream>>>(logits, trans, out);
}

// Round 3
// 2717.303 us; speedup vs baseline: 1.0604x; 1.0604x over previous
//
#include <hip/hip_runtime.h>
#include <cmath>

// Problem constants
#define B_   512
#define L_   200
#define V_   50000
#define E_   256
#define H_   128     // per-direction hidden
#define G4H_ 512     // 4*H
#define D_   256     // 2*H
#define T_   6

__device__ __forceinline__ float sigmoidf_(float x) { return 1.0f / (1.0f + __expf(-x)); }
__device__ __forceinline__ float leakyf_(float x)   { return x >= 0.0f ? x : 0.01f * x; }

// ---------------------------------------------------------------------------
// K1: xg GEMM for a time-chunk, both directions.
// Tiles: BM=64, BN=128, BK=16, 256 threads, 4x8 micro-tile.
// ---------------------------------------------------------------------------
#define BM 64
#define BN 128
#define BK 16

__global__ __launch_bounds__(256) void gemm_xg_chunk(
    const int* __restrict__ sent, const float* __restrict__ emb,
    const float* __restrict__ Wf, const float* __restrict__ Wb,
    const float* __restrict__ bihf, const float* __restrict__ bhhf,
    const float* __restrict__ bihb, const float* __restrict__ bhhb,
    float* __restrict__ xgc, int c0, int tc)
{
    __shared__ float As[BK][BM];
    __shared__ float Bs[BK][BN];
    __shared__ int   tok[BM];

    const int bm  = blockIdx.x;       // 0 .. 16*tc-1
    const int bn  = blockIdx.y;       // 0..3 (N=512 per dir)
    const int tid = threadIdx.x;
    const int half = B_ * tc;         // rows per direction
    const int dir  = (bm * BM) >= half;   // uniform per block (B*tc % 64 == 0)

    if (tid < BM) {
        const int vm  = bm * BM + tid;
        const int rem = vm - dir * half;
        const int b   = rem / tc;
        const int ti  = rem - b * tc;
        const int s   = c0 + ti;
        const int t   = dir ? (L_ - 1 - s) : s;
        tok[tid] = sent[b * L_ + t];
    }
    __syncthreads();

    const int tx = tid & 15;    // n groups of 8
    const int ty = tid >> 4;    // m groups of 4
    const int n0 = bn * BN;

    const float* W   = dir ? Wb   : Wf;
    const float* bih = dir ? bihb : bihf;
    const float* bhh = dir ? bhhb : bhhf;

    float acc[4][8];
#pragma unroll
    for (int i = 0; i < 4; ++i)
#pragma unroll
        for (int j = 0; j < 8; ++j) acc[i][j] = 0.0f;

    const int lrow = tid >> 2;          // 0..63
    const int lk   = (tid & 3) * 4;     // 0,4,8,12

    for (int k0 = 0; k0 < E_; k0 += BK) {
        // stage A (gathered from embedding)
        {
            const float4 v = *(const float4*)(emb + (size_t)tok[lrow] * E_ + k0 + lk);
            As[lk + 0][lrow] = v.x; As[lk + 1][lrow] = v.y;
            As[lk + 2][lrow] = v.z; As[lk + 3][lrow] = v.w;
        }
        // stage B = W^T (two passes of 64 rows)
#pragma unroll
        for (int p = 0; p < 2; ++p) {
            const int n = p * 64 + lrow;
            const float4 v = *(const float4*)(W + (size_t)(n0 + n) * E_ + k0 + lk);
            Bs[lk + 0][n] = v.x; Bs[lk + 1][n] = v.y;
            Bs[lk + 2][n] = v.z; Bs[lk + 3][n] = v.w;
        }
        __syncthreads();

#pragma unroll
        for (int k = 0; k < BK; ++k) {
            float a[4], bb[8];
            *(float4*)a        = *(const float4*)&As[k][ty * 4];
            *(float4*)(bb)     = *(const float4*)&Bs[k][tx * 8];
            *(float4*)(bb + 4) = *(const float4*)&Bs[k][tx * 8 + 4];
#pragma unroll
            for (int i = 0; i < 4; ++i)
#pragma unroll
                for (int j = 0; j < 8; ++j) acc[i][j] += a[i] * bb[j];
        }
        __syncthreads();
    }

    // epilogue: add bias, store vm-major
    const int nb = n0 + tx * 8;
    float bias[8];
#pragma unroll
    for (int j = 0; j < 8; ++j) bias[j] = bih[nb + j] + bhh[nb + j];
#pragma unroll
    for (int i = 0; i < 4; ++i) {
        const int vm = bm * BM + ty * 4 + i;
        float* dst = xgc + (size_t)vm * G4H_ + nb;
        float4 v0, v1;
        v0.x = acc[i][0] + bias[0]; v0.y = acc[i][1] + bias[1];
        v0.z = acc[i][2] + bias[2]; v0.w = acc[i][3] + bias[3];
        v1.x = acc[i][4] + bias[4]; v1.y = acc[i][5] + bias[5];
        v1.z = acc[i][6] + bias[6]; v1.w = acc[i][7] + bias[7];
        *(float4*)dst       = v0;
        *(float4*)(dst + 4) = v1;
    }
}

// ---------------------------------------------------------------------------
// K2: LSTM scan over one time-chunk (unchanged this round).
// ---------------------------------------------------------------------------
#define GS 4

__global__ __launch_bounds__(512, 2) void lstm_scan_chunk(
    const float* __restrict__ xgc,
    const float* __restrict__ Whh_f, const float* __restrict__ Whh_b,
    float* __restrict__ state, float* __restrict__ hcat, int c0, int tc)
{
    const int wg  = blockIdx.x;      // 0..255
    const int dir = wg >> 7;
    const int b0  = (wg & 127) * GS;
    const int r   = threadIdx.x;     // 0..511

    const float* Whh = dir ? Whh_b : Whh_f;

    float w[H_];
#pragma unroll
    for (int k = 0; k < H_; k += 4) {
        const float4 v = *(const float4*)(Whh + (size_t)r * H_ + k);
        w[k] = v.x; w[k + 1] = v.y; w[k + 2] = v.z; w[k + 3] = v.w;
    }

    __shared__ float h_s[H_][GS];
    __shared__ float g_s[G4H_][GS];

    float c[GS] = {0.f, 0.f, 0.f, 0.f};   // live only for r < H_
    if (r < H_) {
        if (c0 == 0) {
            *(float4*)&h_s[r][0] = make_float4(0.f, 0.f, 0.f, 0.f);
        } else {
#pragma unroll
            for (int s = 0; s < GS; ++s) {
                h_s[r][s] = state[((size_t)(dir * B_ + b0 + s) * 2 + 0) * H_ + r];
                c[s]      = state[((size_t)(dir * B_ + b0 + s) * 2 + 1) * H_ + r];
            }
        }
    }

    const int t0    = dir ? (L_ - 1 - c0) : c0;
    const int hstep = dir ? -D_ : D_;

    const float* xp[GS];
    float* hp[GS];
#pragma unroll
    for (int s = 0; s < GS; ++s) {
        xp[s] = xgc + ((size_t)(dir * B_ + b0 + s) * tc) * G4H_ + r;
        hp[s] = hcat + ((size_t)(b0 + s) * L_ + t0) * D_ + dir * H_ + r;
    }
    __syncthreads();

    for (int t = 0; t < tc; ++t) {
        float a0 = xp[0][0], a1 = xp[1][0], a2 = xp[2][0], a3 = xp[3][0];
#pragma unroll
        for (int s = 0; s < GS; ++s) xp[s] += G4H_;

#pragma unroll
        for (int k = 0; k < H_; ++k) {
            const float4 hv = *(const float4*)&h_s[k][0];
            a0 += w[k] * hv.x;
            a1 += w[k] * hv.y;
            a2 += w[k] * hv.z;
            a3 += w[k] * hv.w;
        }
        *(float4*)&g_s[r][0] = make_float4(a0, a1, a2, a3);
        __syncthreads();

        if (r < H_) {
            const float4 gi = *(const float4*)&g_s[r][0];
            const float4 gf = *(const float4*)&g_s[r + H_][0];
            const float4 gg = *(const float4*)&g_s[r + 2 * H_][0];
            const float4 go = *(const float4*)&g_s[r + 3 * H_][0];
            float hv[GS];
            c[0] = sigmoidf_(gf.x) * c[0] + sigmoidf_(gi.x) * tanhf(gg.x);
            hv[0] = sigmoidf_(go.x) * tanhf(c[0]);
            c[1] = sigmoidf_(gf.y) * c[1] + sigmoidf_(gi.y) * tanhf(gg.y);
            hv[1] = sigmoidf_(go.y) * tanhf(c[1]);
            c[2] = sigmoidf_(gf.z) * c[2] + sigmoidf_(gi.z) * tanhf(gg.z);
            hv[2] = sigmoidf_(go.z) * tanhf(c[2]);
            c[3] = sigmoidf_(gf.w) * c[3] + sigmoidf_(gi.w) * tanhf(gg.w);
            hv[3] = sigmoidf_(go.w) * tanhf(c[3]);
            *(float4*)&h_s[r][0] = make_float4(hv[0], hv[1], hv[2], hv[3]);
#pragma unroll
            for (int s = 0; s < GS; ++s) { hp[s][0] = hv[s]; hp[s] += hstep; }
        }
        __syncthreads();
    }

    if (r < H_) {
#pragma unroll
        for (int s = 0; s < GS; ++s) {
            state[((size_t)(dir * B_ + b0 + s) * 2 + 0) * H_ + r] = h_s[r][s];
            state[((size_t)(dir * B_ + b0 + s) * 2 + 1) * H_ + r] = c[s];
        }
    }
}

// ---------------------------------------------------------------------------
// K3 v2: fused MLP1 + MLP2 + tag projection.
// 64 rows/block, 256 threads, 4x8 micro-tile for both GEMMs.
// Pipelined over n-chunks of 128: GEMM1's n-dim is GEMM2's k-dim, so only a
// 128x68 h1-transpose tile lives in LDS (stride 68: GEMM2 A-reads are
// 16B-aligned 4-bank broadcasts, conflict-free). h2 stays in registers;
// tag projection reduced across the 16 tx-lanes with __shfl_xor.
// LDS ~55 KB -> 2 blocks/CU.
// ---------------------------------------------------------------------------
#define S1T 68   // h1T row stride (multiple of 4 for alignment)

__global__ __launch_bounds__(256) void fused_mlp(
    const float* __restrict__ hcat,
    const float* __restrict__ W1, const float* __restrict__ b1,
    const float* __restrict__ W2, const float* __restrict__ b2,
    const float* __restrict__ Wt, const float* __restrict__ bt,
    float* __restrict__ logits)
{
    __shared__ float As[BK][BM];        // hcat k-slice, [k][m]
    __shared__ float Bs[BK][BN];        // W slice, [k][n]
    __shared__ float h1T[BN][S1T];      // h1 chunk, [k_local][m]
    __shared__ float Wt_s[T_][D_ + 2];
    __shared__ float b1_s[D_], b2_s[D_], bt_s[T_];

    const int tid  = threadIdx.x;
    const int row0 = blockIdx.x * BM;

    for (int i = tid; i < T_ * D_; i += 256) Wt_s[i >> 8][i & 255] = Wt[i];
    b1_s[tid] = b1[tid];
    b2_s[tid] = b2[tid];
    if (tid < T_) bt_s[tid] = bt[tid];

    const int tx = tid & 15;            // n groups of 8
    const int ty = tid >> 4;            // m groups of 4
    const int lrow = tid >> 2;          // staging row 0..63
    const int lk   = (tid & 3) * 4;     // staging k 0,4,8,12

    float acc2[2][4][8];
#pragma unroll
    for (int q = 0; q < 2; ++q)
#pragma unroll
        for (int i = 0; i < 4; ++i)
#pragma unroll
            for (int j = 0; j < 8; ++j) acc2[q][i][j] = 0.0f;

    for (int n0t = 0; n0t < 2; ++n0t) {
        const int n0 = n0t * BN;

        // ---- GEMM1: h1[:, n0:n0+128] = hcat_tile @ W1^T ----
        float acc1[4][8];
#pragma unroll
        for (int i = 0; i < 4; ++i)
#pragma unroll
            for (int j = 0; j < 8; ++j) acc1[i][j] = 0.0f;

        for (int k0 = 0; k0 < D_; k0 += BK) {
            {
                const float4 v = *(const float4*)(hcat + (size_t)(row0 + lrow) * D_ + k0 + lk);
                As[lk + 0][lrow] = v.x; As[lk + 1][lrow] = v.y;
                As[lk + 2][lrow] = v.z; As[lk + 3][lrow] = v.w;
            }
#pragma unroll
            for (int p = 0; p < 2; ++p) {
                const int n = p * 64 + lrow;
                const float4 v = *(const float4*)(W1 + (size_t)(n0 + n) * D_ + k0 + lk);
                Bs[lk + 0][n] = v.x; Bs[lk + 1][n] = v.y;
                Bs[lk + 2][n] = v.z; Bs[lk + 3][n] = v.w;
            }
            __syncthreads();
#pragma unroll
            for (int k = 0; k < BK; ++k) {
                float a[4], bb[8];
                *(float4*)a        = *(const float4*)&As[k][ty * 4];
                *(float4*)(bb)     = *(const float4*)&Bs[k][tx * 8];
                *(float4*)(bb + 4) = *(const float4*)&Bs[k][tx * 8 + 4];
#pragma unroll
                for (int i = 0; i < 4; ++i)
#pragma unroll
                    for (int j = 0; j < 8; ++j) acc1[i][j] += a[i] * bb[j];
            }
            __syncthreads();
        }

        // h1 (+bias, leaky) -> h1T[k_local][m]  (float4 over m; one-time cost)
#pragma unroll
        for (int j = 0; j < 8; ++j) {
            const int nl = tx * 8 + j;
            const float bv = b1_s[n0 + nl];
            float4 v;
            v.x = leakyf_(acc1[0][j] + bv);
            v.y = leakyf_(acc1[1][j] + bv);
            v.z = leakyf_(acc1[2][j] + bv);
            v.w = leakyf_(acc1[3][j] + bv);
            *(float4*)&h1T[nl][ty * 4] = v;
        }
        __syncthreads();

        // ---- GEMM2 partial: acc2 += h1[:, n0:n0+128] @ W2[:, n0:n0+128]^T ----
        for (int n2t = 0; n2t < 2; ++n2t) {
            for (int kc = 0; kc < BN; kc += BK) {
#pragma unroll
                for (int p = 0; p < 2; ++p) {
                    const int n = p * 64 + lrow;
                    const float4 v = *(const float4*)(W2 + (size_t)(n2t * BN + n) * D_ + n0 + kc + lk);
                    Bs[lk + 0][n] = v.x; Bs[lk + 1][n] = v.y;
                    Bs[lk + 2][n] = v.z; Bs[lk + 3][n] = v.w;
                }
                __syncthreads();
#pragma unroll
                for (int k = 0; k < BK; ++k) {
                    float a[4], bb[8];
                    *(float4*)a        = *(const float4*)&h1T[kc + k][ty * 4];
                    *(float4*)(bb)     = *(const float4*)&Bs[k][tx * 8];
                    *(float4*)(bb + 4) = *(const float4*)&Bs[k][tx * 8 + 4];
#pragma unroll
                    for (int i = 0; i < 4; ++i)
#pragma unroll
                        for (int j = 0; j < 8; ++j) acc2[n2t][i][j] += a[i] * bb[j];
                }
                __syncthreads();
            }
        }
    }

    // ---- epilogue: h2 = leaky(acc2 + b2) in regs; tag partials; shfl reduce ----
    float part[4][T_];
#pragma unroll
    for (int i = 0; i < 4; ++i)
#pragma unroll
        for (int jt = 0; jt < T_; ++jt) part[i][jt] = 0.0f;

#pragma unroll
    for (int q = 0; q < 2; ++q)
#pragma unroll
        for (int j = 0; j < 8; ++j) {
            const int n = q * BN + tx * 8 + j;
            const float bv = b2_s[n];
            float h2v[4];
#pragma unroll
            for (int i = 0; i < 4; ++i) h2v[i] = leakyf_(acc2[q][i][j] + bv);
#pragma unroll
            for (int jt = 0; jt < T_; ++jt) {
                const float wv = Wt_s[jt][n];
#pragma unroll
                for (int i = 0; i < 4; ++i) part[i][jt] += h2v[i] * wv;
            }
        }

#pragma unroll
    for (int m = 1; m <= 8; m <<= 1)
#pragma unroll
        for (int i = 0; i < 4; ++i)
#pragma unroll
            for (int jt = 0; jt < T_; ++jt)
                part[i][jt] += __shfl_xor(part[i][jt], m, 16);

    if (tx == 0) {
#pragma unroll
        for (int i = 0; i < 4; ++i) {
            const int m = row0 + ty * 4 + i;
#pragma unroll
            for (int jt = 0; jt < T_; ++jt)
                logits[(size_t)m * T_ + jt] = leakyf_(part[i][jt] + bt_s[jt]);
        }
    }
}

// ---------------------------------------------------------------------------
// K4: Viterbi per sample. Block = 64 threads (1 wave), grid = B.
// ---------------------------------------------------------------------------
__global__ __launch_bounds__(64) void viterbi_kernel(
    const float* __restrict__ logits, const float* __restrict__ trans,
    float* __restrict__ out)
{
    const int b = blockIdx.x;
    const int lane = threadIdx.x;

    __shared__ float prev[2][8];
    __shared__ unsigned char bp[L_][8];
    __shared__ int path_s[L_];

    float tr[T_];
    if (lane < T_) {
#pragma unroll
        for (int i = 0; i < T_; ++i) tr[i] = trans[i * T_ + lane];
    }
    const float* lg = logits + (size_t)b * L_ * T_;
    if (lane < T_) prev[0][lane] = lg[lane];
    __syncthreads();

    int cur = 0;
    for (int t = 1; t < L_; ++t) {
        if (lane < T_) {
            float m = -1e30f; int arg = 0;
#pragma unroll
            for (int i = 0; i < T_; ++i) {
                const float v = prev[cur][i] + tr[i];
                if (v > m) { m = v; arg = i; }
            }
            prev[1 - cur][lane] = lg[t * T_ + lane] + m;
            bp[t][lane] = (unsigned char)arg;
        }
        cur ^= 1;
        __syncthreads();
    }

    if (lane == 0) {
        float best = prev[cur][0]; int tag = 0;
#pragma unroll
        for (int j = 1; j < T_; ++j)
            if (prev[cur][j] > best) { best = prev[cur][j]; tag = j; }
        out[b] = best;
        path_s[L_ - 1] = tag;
        for (int t = L_ - 1; t >= 1; --t) {
            tag = bp[t][tag];
            path_s[t - 1] = tag;
        }
    }
    __syncthreads();
    for (int i = lane; i < L_; i += 64)
        out[B_ + (size_t)b * L_ + i] = (float)path_s[i];
}

// ---------------------------------------------------------------------------
extern "C" void kernel_launch(void* const* d_in, const int* in_sizes, int n_in,
                              void* d_out, int out_size, void* d_ws, size_t ws_size,
                              hipStream_t stream)
{
    (void)in_sizes; (void)n_in; (void)out_size;

    const int*   sent  = (const int*)  d_in[0];
    const float* emb   = (const float*)d_in[2];
    const float* Wih_f = (const float*)d_in[3];
    const float* Whh_f = (const float*)d_in[4];
    const float* bih_f = (const float*)d_in[5];
    const float* bhh_f = (const float*)d_in[6];
    const float* Wih_b = (const float*)d_in[7];
    const float* Whh_b = (const float*)d_in[8];
    const float* bih_b = (const float*)d_in[9];
    const float* bhh_b = (const float*)d_in[10];
    const float* W1    = (const float*)d_in[11];
    const float* b1    = (const float*)d_in[12];
    const float* W2    = (const float*)d_in[13];
    const float* b2    = (const float*)d_in[14];
    const float* Wt    = (const float*)d_in[15];
    const float* bt    = (const float*)d_in[16];
    const float* trans = (const float*)d_in[17];

    float* ws = (float*)d_ws;
    const size_t HCAT_E = (size_t)B_ * L_ * D_;     // 26,214,400 floats
    const size_t LG_E   = (size_t)B_ * L_ * T_;     //    614,400
    const size_t ST_E   = (size_t)2 * B_ * 2 * H_;  //    262,144
    float* hcat   = ws;
    float* logits = ws + HCAT_E;
    float* state  = logits + LG_E;
    float* xgc    = state + ST_E;

    // Adaptive time-chunk so the xg staging buffer fits in ws_size.
    const size_t base  = HCAT_E + LG_E + ST_E;      // ~108 MB
    const size_t per_t = (size_t)2 * B_ * G4H_;     // 524,288 floats per timestep
    const size_t ws_f  = ws_size / sizeof(float);
    long long avail = (long long)ws_f - (long long)base;
    int Tc = (avail > 0) ? (int)(avail / (long long)per_t) : 0;
    if (Tc < 1)  Tc = 1;
    if (Tc > L_) Tc = L_;

    float* out = (float*)d_out;

    for (int c0 = 0; c0 < L_; c0 += Tc) {
        const int tc = (L_ - c0 < Tc) ? (L_ - c0) : Tc;
        gemm_xg_chunk<<<dim3(16 * tc, 4), 256, 0, stream>>>(
            sent, emb, Wih_f, Wih_b, bih_f, bhh_f, bih_b, bhh_b, xgc, c0, tc);
        lstm_scan_chunk<<<256, 512, 0, stream>>>(
            xgc, Whh_f, Whh_b, state, hcat, c0, tc);
    }
    fused_mlp<<<(B_ * L_) / BM, 256, 0, stream>>>(
        hcat, W1, b1, W2, b2, Wt, bt, logits);
    viterbi_kernel<<<B_, 64, 0, stream>>>(logits, trans, out);
}

// Round 4
// 2542.923 us; speedup vs baseline: 1.1331x; 1.0686x over previous
//
#include <hip/hip_runtime.h>
#include <cmath>

// Problem constants
#define B_   512
#define L_   200
#define V_   50000
#define E_   256
#define H_   128     // per-direction hidden
#define G4H_ 512     // 4*H
#define D_   256     // 2*H
#define T_   6

__device__ __forceinline__ float sigmoidf_(float x) { return 1.0f / (1.0f + __expf(-x)); }
__device__ __forceinline__ float leakyf_(float x)   { return x >= 0.0f ? x : 0.01f * x; }

// ---------------------------------------------------------------------------
// GEMM tiling constants. Column map per thread: cols tx*4+{0..3} and
// 64+tx*4+{0..3} (2-way bank aliasing = free). As stride 68 / Bs stride 132
// keep staging writes at 2-way and reads 16B-aligned.
// ---------------------------------------------------------------------------
#define BM 64
#define BN 128
#define BK 16
#define ASTR 68
#define BSTR 132

// ---------------------------------------------------------------------------
// K1: xg GEMM for a time-chunk, both directions.
// ---------------------------------------------------------------------------
__global__ __launch_bounds__(256) void gemm_xg_chunk(
    const int* __restrict__ sent, const float* __restrict__ emb,
    const float* __restrict__ Wf, const float* __restrict__ Wb,
    const float* __restrict__ bihf, const float* __restrict__ bhhf,
    const float* __restrict__ bihb, const float* __restrict__ bhhb,
    float* __restrict__ xgc, int c0, int tc)
{
    __shared__ float As[BK][ASTR];
    __shared__ float Bs[BK][BSTR];
    __shared__ int   tok[BM];

    const int bm  = blockIdx.x;       // 0 .. 16*tc-1
    const int bn  = blockIdx.y;       // 0..3 (N=512 per dir)
    const int tid = threadIdx.x;
    const int half = B_ * tc;         // rows per direction
    const int dir  = (bm * BM) >= half;   // uniform per block (B*tc % 64 == 0)

    if (tid < BM) {
        const int vm  = bm * BM + tid;
        const int rem = vm - dir * half;
        const int b   = rem / tc;
        const int ti  = rem - b * tc;
        const int s   = c0 + ti;
        const int t   = dir ? (L_ - 1 - s) : s;
        tok[tid] = sent[b * L_ + t];
    }
    __syncthreads();

    const int tx = tid & 15;    // n: cols tx*4.. and 64+tx*4..
    const int ty = tid >> 4;    // m groups of 4
    const int n0 = bn * BN;

    const float* W   = dir ? Wb   : Wf;
    const float* bih = dir ? bihb : bihf;
    const float* bhh = dir ? bhhb : bhhf;

    float acc[4][8];
#pragma unroll
    for (int i = 0; i < 4; ++i)
#pragma unroll
        for (int j = 0; j < 8; ++j) acc[i][j] = 0.0f;

    const int lrow = tid >> 2;          // 0..63
    const int lk   = (tid & 3) * 4;     // 0,4,8,12

    for (int k0 = 0; k0 < E_; k0 += BK) {
        {
            const float4 v = *(const float4*)(emb + (size_t)tok[lrow] * E_ + k0 + lk);
            As[lk + 0][lrow] = v.x; As[lk + 1][lrow] = v.y;
            As[lk + 2][lrow] = v.z; As[lk + 3][lrow] = v.w;
        }
#pragma unroll
        for (int p = 0; p < 2; ++p) {
            const int n = p * 64 + lrow;
            const float4 v = *(const float4*)(W + (size_t)(n0 + n) * E_ + k0 + lk);
            Bs[lk + 0][n] = v.x; Bs[lk + 1][n] = v.y;
            Bs[lk + 2][n] = v.z; Bs[lk + 3][n] = v.w;
        }
        __syncthreads();

#pragma unroll
        for (int k = 0; k < BK; ++k) {
            float a[4], bb[8];
            *(float4*)a        = *(const float4*)&As[k][ty * 4];
            *(float4*)(bb)     = *(const float4*)&Bs[k][tx * 4];
            *(float4*)(bb + 4) = *(const float4*)&Bs[k][64 + tx * 4];
#pragma unroll
            for (int i = 0; i < 4; ++i)
#pragma unroll
                for (int j = 0; j < 8; ++j) acc[i][j] += a[i] * bb[j];
        }
        __syncthreads();
    }

    // epilogue: add bias, store vm-major; cols tx*4 and 64+tx*4
    const int nb0 = n0 + tx * 4;
    const int nb1 = n0 + 64 + tx * 4;
    float bias[8];
#pragma unroll
    for (int j = 0; j < 4; ++j) {
        bias[j]     = bih[nb0 + j] + bhh[nb0 + j];
        bias[4 + j] = bih[nb1 + j] + bhh[nb1 + j];
    }
#pragma unroll
    for (int i = 0; i < 4; ++i) {
        const int vm = bm * BM + ty * 4 + i;
        float* dst = xgc + (size_t)vm * G4H_;
        float4 v0, v1;
        v0.x = acc[i][0] + bias[0]; v0.y = acc[i][1] + bias[1];
        v0.z = acc[i][2] + bias[2]; v0.w = acc[i][3] + bias[3];
        v1.x = acc[i][4] + bias[4]; v1.y = acc[i][5] + bias[5];
        v1.z = acc[i][6] + bias[6]; v1.w = acc[i][7] + bias[7];
        *(float4*)(dst + nb0) = v0;
        *(float4*)(dst + nb1) = v1;
    }
}

// ---------------------------------------------------------------------------
// K2: LSTM scan over one time-chunk.
// 512 threads: gate phase, thread r owns gate row r (Whh row in VGPRs),
// x-add deferred to loop end (global load hides under 128-FMA loop).
// Nonlin phase: all 512 threads, mapping j=r>>2, s=r&3 (lane-consecutive
// LDS word addresses -> conflict-free). state layout [dir][b][{h,c}][H].
// ---------------------------------------------------------------------------
#define GS 4

__global__ __launch_bounds__(512, 2) void lstm_scan_chunk(
    const float* __restrict__ xgc,
    const float* __restrict__ Whh_f, const float* __restrict__ Whh_b,
    float* __restrict__ state, float* __restrict__ hcat, int c0, int tc)
{
    const int wg  = blockIdx.x;      // 0..255
    const int dir = wg >> 7;
    const int b0  = (wg & 127) * GS;
    const int r   = threadIdx.x;     // 0..511

    const float* Whh = dir ? Whh_b : Whh_f;

    float w[H_];
#pragma unroll
    for (int k = 0; k < H_; k += 4) {
        const float4 v = *(const float4*)(Whh + (size_t)r * H_ + k);
        w[k] = v.x; w[k + 1] = v.y; w[k + 2] = v.z; w[k + 3] = v.w;
    }

    __shared__ float h_s[H_][GS];
    __shared__ float g_s[G4H_][GS];

    // nonlin-phase identity: hidden j, sample s
    const int j_ = r >> 2;
    const int s_ = r & 3;

    float c;                          // cell state for (j_, s_)
    if (c0 == 0) {
        h_s[j_][s_] = 0.0f;
        c = 0.0f;
    } else {
        h_s[j_][s_] = state[((size_t)(dir * B_ + b0 + s_) * 2 + 0) * H_ + j_];
        c           = state[((size_t)(dir * B_ + b0 + s_) * 2 + 1) * H_ + j_];
    }

    const int t0    = dir ? (L_ - 1 - c0) : c0;
    const int hstep = dir ? -D_ : D_;

    const float* xp[GS];
#pragma unroll
    for (int s = 0; s < GS; ++s)
        xp[s] = xgc + ((size_t)(dir * B_ + b0 + s) * tc) * G4H_ + r;
    float* hp = hcat + ((size_t)(b0 + s_) * L_ + t0) * D_ + dir * H_ + j_;

    __syncthreads();

    for (int t = 0; t < tc; ++t) {
        // issue x loads early; they are consumed only after the FMA loop
        const float xv0 = xp[0][0], xv1 = xp[1][0], xv2 = xp[2][0], xv3 = xp[3][0];
#pragma unroll
        for (int s = 0; s < GS; ++s) xp[s] += G4H_;

        float a0 = 0.f, a1 = 0.f, a2 = 0.f, a3 = 0.f;
#pragma unroll
        for (int k = 0; k < H_; ++k) {
            const float4 hv = *(const float4*)&h_s[k][0];
            a0 += w[k] * hv.x;
            a1 += w[k] * hv.y;
            a2 += w[k] * hv.z;
            a3 += w[k] * hv.w;
        }
        *(float4*)&g_s[r][0] = make_float4(a0 + xv0, a1 + xv1, a2 + xv2, a3 + xv3);
        __syncthreads();

        // nonlinearity: all 512 threads, one (hidden, sample) each
        {
            const float gi = g_s[j_][s_];
            const float gf = g_s[j_ + H_][s_];
            const float gg = g_s[j_ + 2 * H_][s_];
            const float go = g_s[j_ + 3 * H_][s_];
            c = sigmoidf_(gf) * c + sigmoidf_(gi) * tanhf(gg);
            const float hv = sigmoidf_(go) * tanhf(c);
            h_s[j_][s_] = hv;
            hp[0] = hv;
            hp += hstep;
        }
        __syncthreads();
    }

    state[((size_t)(dir * B_ + b0 + s_) * 2 + 0) * H_ + j_] = h_s[j_][s_];
    state[((size_t)(dir * B_ + b0 + s_) * 2 + 1) * H_ + j_] = c;
}

// ---------------------------------------------------------------------------
// K3: fused MLP1 + MLP2 + tag projection. 64 rows/block, 256 threads,
// 4x8 micro-tile, conflict-fixed column map + strides. h1 chunk lives in
// h1T[k][m] (stride 68); h2 in registers; tag reduced via __shfl_xor.
// ---------------------------------------------------------------------------
#define S1T 68   // h1T row stride

__global__ __launch_bounds__(256) void fused_mlp(
    const float* __restrict__ hcat,
    const float* __restrict__ W1, const float* __restrict__ b1,
    const float* __restrict__ W2, const float* __restrict__ b2,
    const float* __restrict__ Wt, const float* __restrict__ bt,
    float* __restrict__ logits)
{
    __shared__ float As[BK][ASTR];      // hcat k-slice, [k][m]
    __shared__ float Bs[BK][BSTR];      // W slice, [k][n]
    __shared__ float h1T[BN][S1T];      // h1 chunk, [k_local][m]
    __shared__ float Wt_s[T_][D_ + 2];
    __shared__ float b1_s[D_], b2_s[D_], bt_s[T_];

    const int tid  = threadIdx.x;
    const int row0 = blockIdx.x * BM;

    for (int i = tid; i < T_ * D_; i += 256) Wt_s[i >> 8][i & 255] = Wt[i];
    b1_s[tid] = b1[tid];
    b2_s[tid] = b2[tid];
    if (tid < T_) bt_s[tid] = bt[tid];

    const int tx = tid & 15;
    const int ty = tid >> 4;
    const int lrow = tid >> 2;          // staging row 0..63
    const int lk   = (tid & 3) * 4;     // staging k 0,4,8,12

    float acc2[2][4][8];
#pragma unroll
    for (int q = 0; q < 2; ++q)
#pragma unroll
        for (int i = 0; i < 4; ++i)
#pragma unroll
            for (int j = 0; j < 8; ++j) acc2[q][i][j] = 0.0f;

    for (int n0t = 0; n0t < 2; ++n0t) {
        const int n0 = n0t * BN;

        // ---- GEMM1: h1[:, n0:n0+128] = hcat_tile @ W1^T ----
        float acc1[4][8];
#pragma unroll
        for (int i = 0; i < 4; ++i)
#pragma unroll
            for (int j = 0; j < 8; ++j) acc1[i][j] = 0.0f;

        for (int k0 = 0; k0 < D_; k0 += BK) {
            {
                const float4 v = *(const float4*)(hcat + (size_t)(row0 + lrow) * D_ + k0 + lk);
                As[lk + 0][lrow] = v.x; As[lk + 1][lrow] = v.y;
                As[lk + 2][lrow] = v.z; As[lk + 3][lrow] = v.w;
            }
#pragma unroll
            for (int p = 0; p < 2; ++p) {
                const int n = p * 64 + lrow;
                const float4 v = *(const float4*)(W1 + (size_t)(n0 + n) * D_ + k0 + lk);
                Bs[lk + 0][n] = v.x; Bs[lk + 1][n] = v.y;
                Bs[lk + 2][n] = v.z; Bs[lk + 3][n] = v.w;
            }
            __syncthreads();
#pragma unroll
            for (int k = 0; k < BK; ++k) {
                float a[4], bb[8];
                *(float4*)a        = *(const float4*)&As[k][ty * 4];
                *(float4*)(bb)     = *(const float4*)&Bs[k][tx * 4];
                *(float4*)(bb + 4) = *(const float4*)&Bs[k][64 + tx * 4];
#pragma unroll
                for (int i = 0; i < 4; ++i)
#pragma unroll
                    for (int j = 0; j < 8; ++j) acc1[i][j] += a[i] * bb[j];
            }
            __syncthreads();
        }

        // h1 (+bias, leaky) -> h1T[k_local][m]
#pragma unroll
        for (int j = 0; j < 8; ++j) {
            const int nl = (j < 4) ? (tx * 4 + j) : (64 + tx * 4 + j - 4);
            const float bv = b1_s[n0 + nl];
            float4 v;
            v.x = leakyf_(acc1[0][j] + bv);
            v.y = leakyf_(acc1[1][j] + bv);
            v.z = leakyf_(acc1[2][j] + bv);
            v.w = leakyf_(acc1[3][j] + bv);
            *(float4*)&h1T[nl][ty * 4] = v;
        }
        __syncthreads();

        // ---- GEMM2 partial: acc2 += h1[:, n0:+128] @ W2[:, n0:+128]^T ----
        for (int n2t = 0; n2t < 2; ++n2t) {
            for (int kc = 0; kc < BN; kc += BK) {
#pragma unroll
                for (int p = 0; p < 2; ++p) {
                    const int n = p * 64 + lrow;
                    const float4 v = *(const float4*)(W2 + (size_t)(n2t * BN + n) * D_ + n0 + kc + lk);
                    Bs[lk + 0][n] = v.x; Bs[lk + 1][n] = v.y;
                    Bs[lk + 2][n] = v.z; Bs[lk + 3][n] = v.w;
                }
                __syncthreads();
#pragma unroll
                for (int k = 0; k < BK; ++k) {
                    float a[4], bb[8];
                    *(float4*)a        = *(const float4*)&h1T[kc + k][ty * 4];
                    *(float4*)(bb)     = *(const float4*)&Bs[k][tx * 4];
                    *(float4*)(bb + 4) = *(const float4*)&Bs[k][64 + tx * 4];
#pragma unroll
                    for (int i = 0; i < 4; ++i)
#pragma unroll
                        for (int j = 0; j < 8; ++j) acc2[n2t][i][j] += a[i] * bb[j];
                }
                __syncthreads();
            }
        }
    }

    // ---- epilogue: h2 = leaky(acc2 + b2) in regs; tag partials; shfl reduce ----
    float part[4][T_];
#pragma unroll
    for (int i = 0; i < 4; ++i)
#pragma unroll
        for (int jt = 0; jt < T_; ++jt) part[i][jt] = 0.0f;

#pragma unroll
    for (int q = 0; q < 2; ++q)
#pragma unroll
        for (int j = 0; j < 8; ++j) {
            const int n = q * BN + ((j < 4) ? (tx * 4 + j) : (64 + tx * 4 + j - 4));
            const float bv = b2_s[n];
            float h2v[4];
#pragma unroll
            for (int i = 0; i < 4; ++i) h2v[i] = leakyf_(acc2[q][i][j] + bv);
#pragma unroll
            for (int jt = 0; jt < T_; ++jt) {
                const float wv = Wt_s[jt][n];
#pragma unroll
                for (int i = 0; i < 4; ++i) part[i][jt] += h2v[i] * wv;
            }
        }

#pragma unroll
    for (int m = 1; m <= 8; m <<= 1)
#pragma unroll
        for (int i = 0; i < 4; ++i)
#pragma unroll
            for (int jt = 0; jt < T_; ++jt)
                part[i][jt] += __shfl_xor(part[i][jt], m, 16);

    if (tx == 0) {
#pragma unroll
        for (int i = 0; i < 4; ++i) {
            const int m = row0 + ty * 4 + i;
#pragma unroll
            for (int jt = 0; jt < T_; ++jt)
                logits[(size_t)m * T_ + jt] = leakyf_(part[i][jt] + bt_s[jt]);
        }
    }
}

// ---------------------------------------------------------------------------
// K4: Viterbi per sample. Single wave, prev in registers, shfl broadcast,
// no barriers in the trellis loop. bp table in LDS for the backtrace.
// ---------------------------------------------------------------------------
__global__ __launch_bounds__(64) void viterbi_kernel(
    const float* __restrict__ logits, const float* __restrict__ trans,
    float* __restrict__ out)
{
    const int b = blockIdx.x;
    const int lane = threadIdx.x;

    __shared__ unsigned char bp[L_][8];
    __shared__ int path_s[L_];

    float tr[T_];   // tr[i] = trans[i][lane] for lane < T_
    if (lane < T_) {
#pragma unroll
        for (int i = 0; i < T_; ++i) tr[i] = trans[i * T_ + lane];
    }
    const float* lg = logits + (size_t)b * L_ * T_;
    float prev = (lane < T_) ? lg[lane] : -1e30f;

    for (int t = 1; t < L_; ++t) {
        float m = -1e30f; int arg = 0;
#pragma unroll
        for (int i = 0; i < T_; ++i) {
            const float v = __shfl(prev, i, 64) + tr[i];
            if (v > m) { m = v; arg = i; }
        }
        const float obs = (lane < T_) ? lg[t * T_ + lane] : 0.0f;
        prev = obs + m;
        if (lane < T_) bp[t][lane] = (unsigned char)arg;
    }
    __syncthreads();

    if (lane == 0) {
        float best = prev; int tag = 0;
#pragma unroll
        for (int jj = 1; jj < T_; ++jj) {
            const float v = __shfl(prev, jj, 64);
            // note: lane 0 executes shfl with all lanes active in this wave?
            // guard: this branch is lane-divergent; use precomputed values instead
            (void)v;
        }
        (void)best; (void)tag;
    }
    // lane-uniform final reduction (all lanes execute; shfl needs active lanes)
    float best = __shfl(prev, 0, 64); int tag = 0;
#pragma unroll
    for (int jj = 1; jj < T_; ++jj) {
        const float v = __shfl(prev, jj, 64);
        if (v > best) { best = v; tag = jj; }
    }
    if (lane == 0) {
        out[b] = best;
        path_s[L_ - 1] = tag;
        for (int t = L_ - 1; t >= 1; --t) {
            tag = bp[t][tag];
            path_s[t - 1] = tag;
        }
    }
    __syncthreads();
    for (int i = lane; i < L_; i += 64)
        out[B_ + (size_t)b * L_ + i] = (float)path_s[i];
}

// ---------------------------------------------------------------------------
extern "C" void kernel_launch(void* const* d_in, const int* in_sizes, int n_in,
                              void* d_out, int out_size, void* d_ws, size_t ws_size,
                              hipStream_t stream)
{
    (void)in_sizes; (void)n_in; (void)out_size;

    const int*   sent  = (const int*)  d_in[0];
    const float* emb   = (const float*)d_in[2];
    const float* Wih_f = (const float*)d_in[3];
    const float* Whh_f = (const float*)d_in[4];
    const float* bih_f = (const float*)d_in[5];
    const float* bhh_f = (const float*)d_in[6];
    const float* Wih_b = (const float*)d_in[7];
    const float* Whh_b = (const float*)d_in[8];
    const float* bih_b = (const float*)d_in[9];
    const float* bhh_b = (const float*)d_in[10];
    const float* W1    = (const float*)d_in[11];
    const float* b1    = (const float*)d_in[12];
    const float* W2    = (const float*)d_in[13];
    const float* b2    = (const float*)d_in[14];
    const float* Wt    = (const float*)d_in[15];
    const float* bt    = (const float*)d_in[16];
    const float* trans = (const float*)d_in[17];

    float* ws = (float*)d_ws;
    const size_t HCAT_E = (size_t)B_ * L_ * D_;     // 26,214,400 floats
    const size_t LG_E   = (size_t)B_ * L_ * T_;     //    614,400
    const size_t ST_E   = (size_t)2 * B_ * 2 * H_;  //    262,144
    float* hcat   = ws;
    float* logits = ws + HCAT_E;
    float* state  = logits + LG_E;
    float* xgc    = state + ST_E;

    // Adaptive time-chunk so the xg staging buffer fits in ws_size.
    const size_t base  = HCAT_E + LG_E + ST_E;      // ~108 MB
    const size_t per_t = (size_t)2 * B_ * G4H_;     // 524,288 floats per timestep
    const size_t ws_f  = ws_size / sizeof(float);
    long long avail = (long long)ws_f - (long long)base;
    int Tc = (avail > 0) ? (int)(avail / (long long)per_t) : 0;
    if (Tc < 1)  Tc = 1;
    if (Tc > L_) Tc = L_;

    float* out = (float*)d_out;

    for (int c0 = 0; c0 < L_; c0 += Tc) {
        const int tc = (L_ - c0 < Tc) ? (L_ - c0) : Tc;
        gemm_xg_chunk<<<dim3(16 * tc, 4), 256, 0, stream>>>(
            sent, emb, Wih_f, Wih_b, bih_f, bhh_f, bih_b, bhh_b, xgc, c0, tc);
        lstm_scan_chunk<<<256, 512, 0, stream>>>(
            xgc, Whh_f, Whh_b, state, hcat, c0, tc);
    }
    fused_mlp<<<(B_ * L_) / BM, 256, 0, stream>>>(
        hcat, W1, b1, W2, b2, Wt, bt, logits);
    viterbi_kernel<<<B_, 64, 0, stream>>>(logits, trans, out);
}